// Round 4
// baseline (651.164 us; speedup 1.0000x reference)
//
#include <hip/hip_runtime.h>
#include <hip/hip_fp16.h>

#define N    8192
#define FIN  256
#define FOUT 128
#define BM   64
#define BN   64

typedef _Float16 half8 __attribute__((ext_vector_type(8)));
typedef _Float16 half4v __attribute__((ext_vector_type(4)));
typedef float floatx4 __attribute__((ext_vector_type(4)));

// ---------------------------------------------------------------------------
// Mask-prep: stream adj (268 MB) coalesced (int4/lane), pack bits via ballot.
// Layout: Msk[row][g][e] (u64), bit l <-> adj[row][g*256 + 4*l + e].
// ---------------------------------------------------------------------------
__global__ __launch_bounds__(256)
void maskprep_kernel(const int* __restrict__ adj,
                     unsigned long long* __restrict__ Msk)
{
    const int tid  = threadIdx.x;
    const int wave = tid >> 6;
    const int lane = tid & 63;
    const int task = blockIdx.x * 4 + wave;
    const int row  = task >> 3;
    const int g0   = (task & 7) * 4;
    const int4* base = (const int4*)(adj + (size_t)row * N);
#pragma unroll
    for (int gg = 0; gg < 4; gg++) {
        int g = g0 + gg;
        int4 v = base[g * 64 + lane];
        unsigned long long b0 = __ballot(v.x != 0);
        unsigned long long b1 = __ballot(v.y != 0);
        unsigned long long b2 = __ballot(v.z != 0);
        unsigned long long b3 = __ballot(v.w != 0);
        if (lane == 0) {
            unsigned long long* p = &Msk[((size_t)row * 32 + g) * 4];
            p[0] = b0; p[1] = b1; p[2] = b2; p[3] = b3;
        }
    }
}

// ---------------------------------------------------------------------------
// W-prep: WT[w][n][k] = fp16(W_w[k][n]); 3 x 128 x 256 fp16 (192 KB).
// ---------------------------------------------------------------------------
__global__ __launch_bounds__(256)
void wprep_kernel(const float* __restrict__ W0,
                  const float* __restrict__ W1,
                  const float* __restrict__ W2,
                  _Float16* __restrict__ WT)
{
    int idx = blockIdx.x * 256 + threadIdx.x;
    int w = idx >> 15;
    int rem = idx & 32767;
    int k = rem >> 7;
    int n = rem & 127;
    const float* Wp = w == 0 ? W0 : (w == 1 ? W1 : W2);
    WT[(size_t)w * 32768 + (size_t)n * FIN + k] = (_Float16)Wp[(size_t)k * FOUT + n];
}

// ---------------------------------------------------------------------------
// H = fp16(inp@W), H2 = fp16(inp@W2), H3T = fp16((inp@W3)^T). Barrier-free.
// grid (N/64 rows, 2 col-halves, 3 matrices) = 768 blocks.
// ---------------------------------------------------------------------------
__global__ __launch_bounds__(256, 2)
void gemm3_kernel(const float* __restrict__ inp,
                  const _Float16* __restrict__ WT,
                  _Float16* __restrict__ H,
                  _Float16* __restrict__ H2,
                  _Float16* __restrict__ H3T)
{
    const int which = blockIdx.z;
    const int c0    = blockIdx.y * 64;
    const _Float16* WTw = WT + (size_t)which * 32768;
    const int r0 = blockIdx.x * 64;
    const int tid  = threadIdx.x;
    const int wave = tid >> 6;
    const int lane = tid & 63;
    const int lo16 = lane & 15;
    const int quad = lane >> 4;
    const int r = r0 + wave * 16 + lo16;

    half8 a[8];
#pragma unroll
    for (int kc = 0; kc < 8; kc++) {
        const float* p = &inp[(size_t)r * FIN + kc * 32 + quad * 8];
        float4 v0 = *(const float4*)p;
        float4 v1 = *(const float4*)(p + 4);
        a[kc][0] = (_Float16)v0.x; a[kc][1] = (_Float16)v0.y;
        a[kc][2] = (_Float16)v0.z; a[kc][3] = (_Float16)v0.w;
        a[kc][4] = (_Float16)v1.x; a[kc][5] = (_Float16)v1.y;
        a[kc][6] = (_Float16)v1.z; a[kc][7] = (_Float16)v1.w;
    }

    floatx4 acc[4];
#pragma unroll
    for (int i = 0; i < 4; i++) acc[i] = (floatx4){0.f, 0.f, 0.f, 0.f};

#pragma unroll
    for (int kc = 0; kc < 8; kc++)
#pragma unroll
        for (int nt = 0; nt < 4; nt++) {
            half8 b = *(const half8*)&WTw[(size_t)(c0 + nt * 16 + lo16) * FIN + kc * 32 + quad * 8];
            acc[nt] = __builtin_amdgcn_mfma_f32_16x16x32_f16(a[kc], b, acc[nt], 0, 0, 0);
        }

    const int arow = wave * 16 + quad * 4;
    if (which < 2) {
        _Float16* outp = which == 0 ? H : H2;
#pragma unroll
        for (int nt = 0; nt < 4; nt++)
#pragma unroll
            for (int rr = 0; rr < 4; rr++)
                outp[(size_t)(r0 + arow + rr) * FOUT + c0 + nt * 16 + lo16] = (_Float16)acc[nt][rr];
    } else {
#pragma unroll
        for (int nt = 0; nt < 4; nt++) {
            half4v v;
#pragma unroll
            for (int rr = 0; rr < 4; rr++) v[rr] = (_Float16)acc[nt][rr];
            *(half4v*)&H3T[(size_t)(c0 + nt * 16 + lo16) * N + r0 + arow] = v;
        }
    }
}

// ---------------------------------------------------------------------------
// Flash-style masked attention. Barrier-free; bitmask adjacency; all K/V/mask
// loads for an iteration hoisted into registers (high MLP); XCD-affinity
// swizzle makes each j-slice L2-resident. 1D grid of (N/BM)*JS blocks.
// ---------------------------------------------------------------------------
template<int JS>
__global__ __launch_bounds__(256, 2)
void attn_kernel(const _Float16* __restrict__ Hq,   // [N][128]
                 const _Float16* __restrict__ Hk,   // [N][128]
                 const _Float16* __restrict__ VT,   // [128][N]
                 const unsigned long long* __restrict__ Msk, // [N][32][4]
                 float* __restrict__ Opart,         // [JS][N][128]
                 float* __restrict__ mpart,         // [JS][N]
                 float* __restrict__ lpart)         // [JS][N]
{
    __shared__ _Float16 Ps[4][16][BN + 8];

    const int tid  = threadIdx.x;
    const int wave = tid >> 6;
    const int lane = tid & 63;
    const int lo16 = lane & 15;
    const int quad = lane >> 4;
    const int bid  = blockIdx.x;
    const int js   = bid & (JS - 1);      // XCD affinity: same js -> same XCD
    const int ib   = bid / JS;
    const int i0   = ib * BM;
    const int jbeg = js * (N / JS);
    const int e    = lo16 & 3;
    const int lsh  = lo16 >> 2;

    half8 q[4];
#pragma unroll
    for (int kc = 0; kc < 4; kc++)
        q[kc] = *(const half8*)&Hq[(size_t)(i0 + wave * 16 + lo16) * FOUT + kc * 32 + quad * 8];

    floatx4 O[8];
#pragma unroll
    for (int i = 0; i < 8; i++) O[i] = (floatx4){0.f, 0.f, 0.f, 0.f};
    float m_r[4], l_r[4];
#pragma unroll
    for (int r = 0; r < 4; r++) { m_r[r] = -1e12f; l_r[r] = 0.f; }

    const int arow = i0 + wave * 16 + quad * 4;   // C-layout row base

    for (int it = 0; it < (N / JS) / BN; it++) {
        const int j0 = jbeg + it * BN;
        const int grp = (j0 >> 8) * 4;
        const int bofs = ((j0 & 255) >> 2) + lsh;

        // ---- hoisted loads: ~36 VMEM in flight before any consumption ----
        half8 kf[16];
#pragma unroll
        for (int nt = 0; nt < 4; nt++)
#pragma unroll
            for (int kc = 0; kc < 4; kc++)
                kf[nt * 4 + kc] = *(const half8*)&Hk[(size_t)(j0 + nt * 16 + lo16) * FOUT + kc * 32 + quad * 8];
        half8 vf[16];
#pragma unroll
        for (int nt = 0; nt < 8; nt++)
#pragma unroll
            for (int kc = 0; kc < 2; kc++)
                vf[nt * 2 + kc] = *(const half8*)&VT[(size_t)(nt * 16 + lo16) * N + j0 + kc * 32 + quad * 8];
        unsigned long long mw[4];
#pragma unroll
        for (int r = 0; r < 4; r++)
            mw[r] = Msk[(size_t)(arow + r) * 128 + e + grp];

        // ---- S = Q K^T ----
        floatx4 S[4];
#pragma unroll
        for (int nt = 0; nt < 4; nt++) {
            S[nt] = (floatx4){0.f, 0.f, 0.f, 0.f};
#pragma unroll
            for (int kc = 0; kc < 4; kc++)
                S[nt] = __builtin_amdgcn_mfma_f32_16x16x32_f16(q[kc], kf[nt * 4 + kc], S[nt], 0, 0, 0);
        }

        // LeakyReLU then bitmask (ref order)
        float sv[4][4];
#pragma unroll
        for (int nt = 0; nt < 4; nt++)
#pragma unroll
            for (int r = 0; r < 4; r++) {
                float ev = S[nt][r];
                ev = ev > 0.f ? ev : 0.2f * ev;
                sv[nt][r] = ((mw[r] >> (bofs + nt * 4)) & 1ull) ? ev : -1e12f;
            }

        // row max: 16-lane butterfly within quad
        float alpha[4];
#pragma unroll
        for (int r = 0; r < 4; r++) {
            float v = fmaxf(fmaxf(sv[0][r], sv[1][r]), fmaxf(sv[2][r], sv[3][r]));
#pragma unroll
            for (int d = 1; d < 16; d <<= 1)
                v = fmaxf(v, __shfl_xor(v, d));
            float mn = fmaxf(m_r[r], v);
            alpha[r] = __expf(m_r[r] - mn);
            m_r[r] = mn;
        }

        // P = exp(sv - m); stash fp16 P in per-wave LDS (C-layout positions)
        float rs[4] = {0.f, 0.f, 0.f, 0.f};
#pragma unroll
        for (int nt = 0; nt < 4; nt++)
#pragma unroll
            for (int r = 0; r < 4; r++) {
                float p = __expf(sv[nt][r] - m_r[r]);
                rs[r] += p;
                Ps[wave][quad * 4 + r][nt * 16 + lo16] = (_Float16)p;
            }
#pragma unroll
        for (int r = 0; r < 4; r++) {
            float v = rs[r];
#pragma unroll
            for (int d = 1; d < 16; d <<= 1)
                v += __shfl_xor(v, d);
            l_r[r] = l_r[r] * alpha[r] + v;
#pragma unroll
            for (int nt = 0; nt < 8; nt++)
                O[nt][r] *= alpha[r];
        }

        // wave-private LDS transpose: drain DS writes, then read A-layout
        asm volatile("s_waitcnt lgkmcnt(0)" ::: "memory");

        // ---- O += P V (V already in registers) ----
#pragma unroll
        for (int kc = 0; kc < BN / 32; kc++) {
            half8 pa = *(const half8*)&Ps[wave][lo16][kc * 32 + quad * 8];
#pragma unroll
            for (int nt = 0; nt < 8; nt++)
                O[nt] = __builtin_amdgcn_mfma_f32_16x16x32_f16(pa, vf[nt * 2 + kc], O[nt], 0, 0, 0);
        }
    }

#pragma unroll
    for (int nt = 0; nt < 8; nt++)
#pragma unroll
        for (int r = 0; r < 4; r++)
            Opart[((size_t)js * N + arow + r) * FOUT + nt * 16 + lo16] = O[nt][r];
    if (lo16 == 0) {
#pragma unroll
        for (int r = 0; r < 4; r++) {
            mpart[js * N + arow + r] = m_r[r];
            lpart[js * N + arow + r] = l_r[r];
        }
    }
}

// ---------------------------------------------------------------------------
// Combine j-split partials, normalize, ELU, fp32 out.
// ---------------------------------------------------------------------------
template<int JS>
__global__ __launch_bounds__(256)
void combine_kernel(const float* __restrict__ Opart,
                    const float* __restrict__ mpart,
                    const float* __restrict__ lpart,
                    float* __restrict__ out)
{
    int idx = blockIdx.x * 256 + threadIdx.x;
    int i = idx >> 5;
    int c = (idx & 31) << 2;
    float m[JS];
    float M = -3.0e38f;
#pragma unroll
    for (int s = 0; s < JS; s++) { m[s] = mpart[s * N + i]; M = fmaxf(M, m[s]); }
    float w[JS];
    float L = 0.f;
#pragma unroll
    for (int s = 0; s < JS; s++) { w[s] = __expf(m[s] - M); L += lpart[s * N + i] * w[s]; }
    float4 o = {0.f, 0.f, 0.f, 0.f};
#pragma unroll
    for (int s = 0; s < JS; s++) {
        float4 v = *(const float4*)&Opart[((size_t)s * N + i) * FOUT + c];
        o.x += w[s] * v.x; o.y += w[s] * v.y; o.z += w[s] * v.z; o.w += w[s] * v.w;
    }
    float inv = 1.f / L;
    float r0 = o.x * inv, r1 = o.y * inv, r2 = o.z * inv, r3 = o.w * inv;
    float4 res;
    res.x = r0 > 0.f ? r0 : __expf(r0) - 1.f;
    res.y = r1 > 0.f ? r1 : __expf(r1) - 1.f;
    res.z = r2 > 0.f ? r2 : __expf(r2) - 1.f;
    res.w = r3 > 0.f ? r3 : __expf(r3) - 1.f;
    *(float4*)&out[(size_t)i * FOUT + c] = res;
}

// ---------------------------------------------------------------------------
extern "C" void kernel_launch(void* const* d_in, const int* in_sizes, int n_in,
                              void* d_out, int out_size, void* d_ws, size_t ws_size,
                              hipStream_t stream) {
    const float* inp = (const float*)d_in[0];
    const int*   adj = (const int*)d_in[1];
    const float* W0  = (const float*)d_in[2];
    const float* W1  = (const float*)d_in[3];
    const float* W2  = (const float*)d_in[4];
    float* out = (float*)d_out;

    char* ws = (char*)d_ws;
    _Float16* H   = (_Float16*)(ws);                          // 2 MB
    _Float16* H2  = (_Float16*)(ws + (2u << 20));             // 2 MB
    _Float16* H3T = (_Float16*)(ws + (4u << 20));             // 2 MB
    _Float16* WT  = (_Float16*)(ws + (6u << 20));             // 192 KB
    unsigned long long* Msk = (unsigned long long*)(ws + (7u << 20)); // 8 MB
    float* Opart  = (float*)(ws + (16u << 20));               // JS*4 MB

    const size_t need8 = (16ull << 20) + 8ull * N * FOUT * 4 + 2ull * 8 * N * 4 + (1u << 20);

    maskprep_kernel<<<16384, 256, 0, stream>>>(adj, Msk);
    wprep_kernel<<<(3 * FIN * FOUT) / 256, 256, 0, stream>>>(W0, W1, W2, WT);
    gemm3_kernel<<<dim3(N / 64, 2, 3), 256, 0, stream>>>(inp, WT, H, H2, H3T);

    if (ws_size >= need8) {
        constexpr int JS = 8;
        float* mpart = (float*)(ws + (16u << 20) + (size_t)JS * N * FOUT * 4);
        float* lpart = mpart + (size_t)JS * N;
        attn_kernel<JS><<<(N / BM) * JS, 256, 0, stream>>>(H, H2, H3T, Msk, Opart, mpart, lpart);
        combine_kernel<JS><<<(N * FOUT / 4) / 256, 256, 0, stream>>>(Opart, mpart, lpart, out);
    } else {
        constexpr int JS = 4;
        float* mpart = (float*)(ws + (16u << 20) + (size_t)JS * N * FOUT * 4);
        float* lpart = mpart + (size_t)JS * N;
        attn_kernel<JS><<<(N / BM) * JS, 256, 0, stream>>>(H, H2, H3T, Msk, Opart, mpart, lpart);
        combine_kernel<JS><<<(N * FOUT / 4) / 256, 256, 0, stream>>>(Opart, mpart, lpart, out);
    }
}

// Round 5
// 480.656 us; speedup vs baseline: 1.3547x; 1.3547x over previous
//
#include <hip/hip_runtime.h>
#include <hip/hip_fp16.h>

#define N    8192
#define FIN  256
#define FOUT 128
#define BM   64
#define BN   64

typedef _Float16 half8 __attribute__((ext_vector_type(8)));
typedef _Float16 half4v __attribute__((ext_vector_type(4)));
typedef float floatx4 __attribute__((ext_vector_type(4)));

// ---------------------------------------------------------------------------
// Mask-prep: stream adj (268 MB) coalesced (int4/lane), pack bits via ballot.
// Layout: Msk[row][g][e] (u64), bit l <-> adj[row][g*256 + 4*l + e].
// ---------------------------------------------------------------------------
__global__ __launch_bounds__(256)
void maskprep_kernel(const int* __restrict__ adj,
                     unsigned long long* __restrict__ Msk)
{
    const int tid  = threadIdx.x;
    const int wave = tid >> 6;
    const int lane = tid & 63;
    const int task = blockIdx.x * 4 + wave;
    const int row  = task >> 3;
    const int g0   = (task & 7) * 4;
    const int4* base = (const int4*)(adj + (size_t)row * N);
    int4 v[4];
#pragma unroll
    for (int gg = 0; gg < 4; gg++) v[gg] = base[(g0 + gg) * 64 + lane];
#pragma unroll
    for (int gg = 0; gg < 4; gg++) {
        unsigned long long b0 = __ballot(v[gg].x != 0);
        unsigned long long b1 = __ballot(v[gg].y != 0);
        unsigned long long b2 = __ballot(v[gg].z != 0);
        unsigned long long b3 = __ballot(v[gg].w != 0);
        if (lane == 0) {
            unsigned long long* p = &Msk[((size_t)row * 32 + g0 + gg) * 4];
            *(ulonglong2*)&p[0] = make_ulonglong2(b0, b1);
            *(ulonglong2*)&p[2] = make_ulonglong2(b2, b3);
        }
    }
}

// ---------------------------------------------------------------------------
// W-prep: write W in FRAG-MAJOR fp16 layout for coalesced MFMA B-loads.
// Wf[w][nt(8)][kc(8)][lane(64)][8 f16]; content = W_w[kc*32+quad*8+jj][nt*16+lo16].
// 3*8*8*64 = 12288 threads.
// ---------------------------------------------------------------------------
__global__ __launch_bounds__(256)
void wprep_kernel(const float* __restrict__ W0,
                  const float* __restrict__ W1,
                  const float* __restrict__ W2,
                  _Float16* __restrict__ Wf)
{
    int idx  = blockIdx.x * 256 + threadIdx.x;   // 0..12287
    int lane = idx & 63;
    int frag = idx >> 6;                          // 0..191
    int w    = frag >> 6;                         // 0..2
    int f    = frag & 63;
    int nt   = f >> 3, kc = f & 7;
    int quad = lane >> 4, lo16 = lane & 15;
    const float* Wp = w == 0 ? W0 : (w == 1 ? W1 : W2);
    half8 v;
#pragma unroll
    for (int jj = 0; jj < 8; jj++)
        v[jj] = (_Float16)Wp[(size_t)(kc * 32 + quad * 8 + jj) * FOUT + nt * 16 + lo16];
    *(half8*)&Wf[(size_t)idx * 8] = v;
}

// ---------------------------------------------------------------------------
// H = fp16(inp@W), H2 = fp16(inp@W2), H3T = fp16((inp@W3)^T). Barrier-free,
// B-frags from frag-major Wf (coalesced 1KB loads).
// grid (N/64 rows, 2 col-halves, 3 matrices) = 768 blocks.
// ---------------------------------------------------------------------------
__global__ __launch_bounds__(256, 2)
void gemm3_kernel(const float* __restrict__ inp,
                  const _Float16* __restrict__ Wf,
                  _Float16* __restrict__ H,
                  _Float16* __restrict__ H2,
                  _Float16* __restrict__ H3T)
{
    const int which = blockIdx.z;
    const int c0    = blockIdx.y * 64;
    const _Float16* Wfw = Wf + (size_t)which * 64 * 64 * 8;
    const int r0 = blockIdx.x * 64;
    const int tid  = threadIdx.x;
    const int wave = tid >> 6;
    const int lane = tid & 63;
    const int lo16 = lane & 15;
    const int quad = lane >> 4;
    const int r = r0 + wave * 16 + lo16;

    half8 a[8];
#pragma unroll
    for (int kc = 0; kc < 8; kc++) {
        const float* p = &inp[(size_t)r * FIN + kc * 32 + quad * 8];
        float4 v0 = *(const float4*)p;
        float4 v1 = *(const float4*)(p + 4);
        a[kc][0] = (_Float16)v0.x; a[kc][1] = (_Float16)v0.y;
        a[kc][2] = (_Float16)v0.z; a[kc][3] = (_Float16)v0.w;
        a[kc][4] = (_Float16)v1.x; a[kc][5] = (_Float16)v1.y;
        a[kc][6] = (_Float16)v1.z; a[kc][7] = (_Float16)v1.w;
    }

    floatx4 acc[4];
#pragma unroll
    for (int i = 0; i < 4; i++) acc[i] = (floatx4){0.f, 0.f, 0.f, 0.f};

#pragma unroll
    for (int kc = 0; kc < 8; kc++)
#pragma unroll
        for (int nt = 0; nt < 4; nt++) {
            int ntg = (c0 >> 4) + nt;
            half8 b = *(const half8*)&Wfw[(((size_t)ntg * 8 + kc) * 64 + lane) * 8];
            acc[nt] = __builtin_amdgcn_mfma_f32_16x16x32_f16(a[kc], b, acc[nt], 0, 0, 0);
        }

    const int arow = wave * 16 + quad * 4;
    if (which < 2) {
        _Float16* outp = which == 0 ? H : H2;
#pragma unroll
        for (int nt = 0; nt < 4; nt++)
#pragma unroll
            for (int rr = 0; rr < 4; rr++)
                outp[(size_t)(r0 + arow + rr) * FOUT + c0 + nt * 16 + lo16] = (_Float16)acc[nt][rr];
    } else {
#pragma unroll
        for (int nt = 0; nt < 4; nt++) {
            half4v v;
#pragma unroll
            for (int rr = 0; rr < 4; rr++) v[rr] = (_Float16)acc[nt][rr];
            *(half4v*)&H3T[(size_t)(c0 + nt * 16 + lo16) * N + r0 + arow] = v;
        }
    }
}

// ---------------------------------------------------------------------------
// Repack K: Kf[jb][nt(4)][kc(4)][lane][8] = H2[jb*64+nt*16+lo16][kc*32+quad*8+jj]
// One-shot 2MB; scattered reads, coalesced writes. 131072 threads.
// ---------------------------------------------------------------------------
__global__ __launch_bounds__(256)
void repackK_kernel(const _Float16* __restrict__ H2, _Float16* __restrict__ Kf)
{
    int idx  = blockIdx.x * 256 + threadIdx.x;
    int lane = idx & 63;
    int frag = idx >> 6;           // jb*16 + nt*4 + kc
    int jb = frag >> 4, f = frag & 15, nt = f >> 2, kc = f & 3;
    int quad = lane >> 4, lo16 = lane & 15;
    half8 v = *(const half8*)&H2[(size_t)(jb * 64 + nt * 16 + lo16) * FOUT + kc * 32 + quad * 8];
    *(half8*)&Kf[(size_t)idx * 8] = v;
}

// ---------------------------------------------------------------------------
// Repack V: Vf[jb][nt(8)][kc(2)][lane][8] = H3T[nt*16+lo16][jb*64+kc*32+quad*8+jj]
// ---------------------------------------------------------------------------
__global__ __launch_bounds__(256)
void repackV_kernel(const _Float16* __restrict__ H3T, _Float16* __restrict__ Vf)
{
    int idx  = blockIdx.x * 256 + threadIdx.x;
    int lane = idx & 63;
    int frag = idx >> 6;           // jb*16 + nt*2 + kc
    int jb = frag >> 4, f = frag & 15, nt = f >> 1, kc = f & 1;
    int quad = lane >> 4, lo16 = lane & 15;
    half8 v = *(const half8*)&H3T[(size_t)(nt * 16 + lo16) * N + jb * 64 + kc * 32 + quad * 8];
    *(half8*)&Vf[(size_t)idx * 8] = v;
}

// ---------------------------------------------------------------------------
// Flash-style masked attention. Barrier-free; bitmask adjacency; K/V frags
// loaded as perfectly-coalesced 1KB instructions from frag-major Kf/Vf.
// ---------------------------------------------------------------------------
template<int JS>
__global__ __launch_bounds__(256, 2)
void attn_kernel(const _Float16* __restrict__ Hq,   // [N][128]
                 const _Float16* __restrict__ Kf,   // frag-major
                 const _Float16* __restrict__ Vf,   // frag-major
                 const unsigned long long* __restrict__ Msk, // [N][32][4]
                 float* __restrict__ Opart,         // [JS][N][128]
                 float* __restrict__ mpart,         // [JS][N]
                 float* __restrict__ lpart)         // [JS][N]
{
    __shared__ _Float16 Ps[4][16][BN + 8];

    const int tid  = threadIdx.x;
    const int wave = tid >> 6;
    const int lane = tid & 63;
    const int lo16 = lane & 15;
    const int quad = lane >> 4;
    const int bid  = blockIdx.x;
    const int js   = bid & (JS - 1);      // XCD affinity: same js -> same XCD
    const int ib   = bid / JS;
    const int i0   = ib * BM;
    const int jbeg = js * (N / JS);
    const int e    = lo16 & 3;
    const int lsh  = lo16 >> 2;

    half8 q[4];
#pragma unroll
    for (int kc = 0; kc < 4; kc++)
        q[kc] = *(const half8*)&Hq[(size_t)(i0 + wave * 16 + lo16) * FOUT + kc * 32 + quad * 8];

    floatx4 O[8];
#pragma unroll
    for (int i = 0; i < 8; i++) O[i] = (floatx4){0.f, 0.f, 0.f, 0.f};
    float m_r[4], l_r[4];
#pragma unroll
    for (int r = 0; r < 4; r++) { m_r[r] = -1e12f; l_r[r] = 0.f; }

    const int arow = i0 + wave * 16 + quad * 4;   // C-layout row base

    for (int it = 0; it < (N / JS) / BN; it++) {
        const int j0 = jbeg + it * BN;
        const int jb = j0 >> 6;
        const int grp = (j0 >> 8) * 4;
        const int bofs = ((j0 & 255) >> 2) + lsh;

        // ---- coalesced frag loads: lane-contiguous 1KB per instruction ----
        const _Float16* kfp = Kf + (size_t)jb * 16 * 64 * 8;
        half8 kf[16];
#pragma unroll
        for (int f = 0; f < 16; f++)
            kf[f] = *(const half8*)&kfp[((size_t)f * 64 + lane) * 8];
        const _Float16* vfp = Vf + (size_t)jb * 16 * 64 * 8;
        half8 vf[16];
#pragma unroll
        for (int f = 0; f < 16; f++)
            vf[f] = *(const half8*)&vfp[((size_t)f * 64 + lane) * 8];
        unsigned long long mw[4];
#pragma unroll
        for (int r = 0; r < 4; r++)
            mw[r] = Msk[(size_t)(arow + r) * 128 + e + grp];

        // ---- S = Q K^T ----
        floatx4 S[4];
#pragma unroll
        for (int nt = 0; nt < 4; nt++) {
            S[nt] = (floatx4){0.f, 0.f, 0.f, 0.f};
#pragma unroll
            for (int kc = 0; kc < 4; kc++)
                S[nt] = __builtin_amdgcn_mfma_f32_16x16x32_f16(q[kc], kf[nt * 4 + kc], S[nt], 0, 0, 0);
        }

        // LeakyReLU then bitmask (ref order)
        float sv[4][4];
#pragma unroll
        for (int nt = 0; nt < 4; nt++)
#pragma unroll
            for (int r = 0; r < 4; r++) {
                float ev = S[nt][r];
                ev = ev > 0.f ? ev : 0.2f * ev;
                sv[nt][r] = ((mw[r] >> (bofs + nt * 4)) & 1ull) ? ev : -1e12f;
            }

        // row max: 16-lane butterfly within quad
        float alpha[4];
#pragma unroll
        for (int r = 0; r < 4; r++) {
            float v = fmaxf(fmaxf(sv[0][r], sv[1][r]), fmaxf(sv[2][r], sv[3][r]));
#pragma unroll
            for (int d = 1; d < 16; d <<= 1)
                v = fmaxf(v, __shfl_xor(v, d));
            float mn = fmaxf(m_r[r], v);
            alpha[r] = __expf(m_r[r] - mn);
            m_r[r] = mn;
        }

        // P = exp(sv - m); stash fp16 P in per-wave LDS (C-layout positions)
        float rs[4] = {0.f, 0.f, 0.f, 0.f};
#pragma unroll
        for (int nt = 0; nt < 4; nt++)
#pragma unroll
            for (int r = 0; r < 4; r++) {
                float p = __expf(sv[nt][r] - m_r[r]);
                rs[r] += p;
                Ps[wave][quad * 4 + r][nt * 16 + lo16] = (_Float16)p;
            }
#pragma unroll
        for (int r = 0; r < 4; r++) {
            float v = rs[r];
#pragma unroll
            for (int d = 1; d < 16; d <<= 1)
                v += __shfl_xor(v, d);
            l_r[r] = l_r[r] * alpha[r] + v;
#pragma unroll
            for (int nt = 0; nt < 8; nt++)
                O[nt][r] *= alpha[r];
        }

        // wave-private LDS transpose: drain DS writes, then read A-layout
        asm volatile("s_waitcnt lgkmcnt(0)" ::: "memory");

        // ---- O += P V (V already in registers) ----
#pragma unroll
        for (int kc = 0; kc < BN / 32; kc++) {
            half8 pa = *(const half8*)&Ps[wave][lo16][kc * 32 + quad * 8];
#pragma unroll
            for (int nt = 0; nt < 8; nt++)
                O[nt] = __builtin_amdgcn_mfma_f32_16x16x32_f16(pa, vf[nt * 2 + kc], O[nt], 0, 0, 0);
        }
    }

#pragma unroll
    for (int nt = 0; nt < 8; nt++)
#pragma unroll
        for (int r = 0; r < 4; r++)
            Opart[((size_t)js * N + arow + r) * FOUT + nt * 16 + lo16] = O[nt][r];
    if (lo16 == 0) {
#pragma unroll
        for (int r = 0; r < 4; r++) {
            mpart[js * N + arow + r] = m_r[r];
            lpart[js * N + arow + r] = l_r[r];
        }
    }
}

// ---------------------------------------------------------------------------
// Combine j-split partials, normalize, ELU, fp32 out.
// ---------------------------------------------------------------------------
template<int JS>
__global__ __launch_bounds__(256)
void combine_kernel(const float* __restrict__ Opart,
                    const float* __restrict__ mpart,
                    const float* __restrict__ lpart,
                    float* __restrict__ out)
{
    int idx = blockIdx.x * 256 + threadIdx.x;
    int i = idx >> 5;
    int c = (idx & 31) << 2;
    float m[JS];
    float M = -3.0e38f;
#pragma unroll
    for (int s = 0; s < JS; s++) { m[s] = mpart[s * N + i]; M = fmaxf(M, m[s]); }
    float w[JS];
    float L = 0.f;
#pragma unroll
    for (int s = 0; s < JS; s++) { w[s] = __expf(m[s] - M); L += lpart[s * N + i] * w[s]; }
    float4 o = {0.f, 0.f, 0.f, 0.f};
#pragma unroll
    for (int s = 0; s < JS; s++) {
        float4 v = *(const float4*)&Opart[((size_t)s * N + i) * FOUT + c];
        o.x += w[s] * v.x; o.y += w[s] * v.y; o.z += w[s] * v.z; o.w += w[s] * v.w;
    }
    float inv = 1.f / L;
    float r0 = o.x * inv, r1 = o.y * inv, r2 = o.z * inv, r3 = o.w * inv;
    float4 res;
    res.x = r0 > 0.f ? r0 : __expf(r0) - 1.f;
    res.y = r1 > 0.f ? r1 : __expf(r1) - 1.f;
    res.z = r2 > 0.f ? r2 : __expf(r2) - 1.f;
    res.w = r3 > 0.f ? r3 : __expf(r3) - 1.f;
    *(float4*)&out[(size_t)i * FOUT + c] = res;
}

// ---------------------------------------------------------------------------
extern "C" void kernel_launch(void* const* d_in, const int* in_sizes, int n_in,
                              void* d_out, int out_size, void* d_ws, size_t ws_size,
                              hipStream_t stream) {
    const float* inp = (const float*)d_in[0];
    const int*   adj = (const int*)d_in[1];
    const float* W0  = (const float*)d_in[2];
    const float* W1  = (const float*)d_in[3];
    const float* W2  = (const float*)d_in[4];
    float* out = (float*)d_out;

    char* ws = (char*)d_ws;
    _Float16* H   = (_Float16*)(ws);                          // 2 MB
    _Float16* H2  = (_Float16*)(ws + (2u << 20));             // 2 MB
    _Float16* H3T = (_Float16*)(ws + (4u << 20));             // 2 MB
    _Float16* Wf  = (_Float16*)(ws + (6u << 20));             // 192 KB
    unsigned long long* Msk = (unsigned long long*)(ws + (7u << 20)); // 8 MB
    _Float16* Kf  = (_Float16*)(ws + (15u << 20));            // 2 MB
    _Float16* Vf  = (_Float16*)(ws + (17u << 20));            // 2 MB
    float* Opart  = (float*)(ws + (19u << 20));               // JS*4 MB

    const size_t need8 = (19ull << 20) + 8ull * N * FOUT * 4 + 2ull * 8 * N * 4;

    maskprep_kernel<<<16384, 256, 0, stream>>>(adj, Msk);
    wprep_kernel<<<48, 256, 0, stream>>>(W0, W1, W2, Wf);
    gemm3_kernel<<<dim3(N / 64, 2, 3), 256, 0, stream>>>(inp, Wf, H, H2, H3T);
    repackK_kernel<<<512, 256, 0, stream>>>(H2, Kf);
    repackV_kernel<<<512, 256, 0, stream>>>(H3T, Vf);

    if (ws_size >= need8) {
        constexpr int JS = 8;
        float* mpart = (float*)(ws + (19u << 20) + (size_t)JS * N * FOUT * 4);
        float* lpart = mpart + (size_t)JS * N;
        attn_kernel<JS><<<(N / BM) * JS, 256, 0, stream>>>(H, Kf, Vf, Msk, Opart, mpart, lpart);
        combine_kernel<JS><<<(N * FOUT / 4) / 256, 256, 0, stream>>>(Opart, mpart, lpart, out);
    } else {
        constexpr int JS = 4;
        float* mpart = (float*)(ws + (19u << 20) + (size_t)JS * N * FOUT * 4);
        float* lpart = mpart + (size_t)JS * N;
        attn_kernel<JS><<<(N / BM) * JS, 256, 0, stream>>>(H, Kf, Vf, Msk, Opart, mpart, lpart);
        combine_kernel<JS><<<(N * FOUT / 4) / 256, 256, 0, stream>>>(Opart, mpart, lpart, out);
    }
}

// Round 6
// 477.942 us; speedup vs baseline: 1.3624x; 1.0057x over previous
//
#include <hip/hip_runtime.h>
#include <hip/hip_fp16.h>

#define N    8192
#define FIN  256
#define FOUT 128
#define BM   64
#define BN   64

typedef _Float16 half8 __attribute__((ext_vector_type(8)));
typedef _Float16 half4v __attribute__((ext_vector_type(4)));
typedef float floatx4 __attribute__((ext_vector_type(4)));

// ---------------------------------------------------------------------------
// Mask-prep: stream adj (268 MB) coalesced (int4/lane), pack bits via ballot.
// Layout: Msk[row][g][e] (u64), bit l <-> adj[row][g*256 + 4*l + e].
// ---------------------------------------------------------------------------
__global__ __launch_bounds__(256)
void maskprep_kernel(const int* __restrict__ adj,
                     unsigned long long* __restrict__ Msk)
{
    const int tid  = threadIdx.x;
    const int wave = tid >> 6;
    const int lane = tid & 63;
    const int task = blockIdx.x * 4 + wave;
    const int row  = task >> 3;
    const int g0   = (task & 7) * 4;
    const int4* base = (const int4*)(adj + (size_t)row * N);
    int4 v[4];
#pragma unroll
    for (int gg = 0; gg < 4; gg++) v[gg] = base[(g0 + gg) * 64 + lane];
#pragma unroll
    for (int gg = 0; gg < 4; gg++) {
        unsigned long long b0 = __ballot(v[gg].x != 0);
        unsigned long long b1 = __ballot(v[gg].y != 0);
        unsigned long long b2 = __ballot(v[gg].z != 0);
        unsigned long long b3 = __ballot(v[gg].w != 0);
        if (lane == 0) {
            unsigned long long* p = &Msk[((size_t)row * 32 + g0 + gg) * 4];
            *(ulonglong2*)&p[0] = make_ulonglong2(b0, b1);
            *(ulonglong2*)&p[2] = make_ulonglong2(b2, b3);
        }
    }
}

// ---------------------------------------------------------------------------
// W-prep: frag-major fp16 W for coalesced MFMA B-loads.
// ---------------------------------------------------------------------------
__global__ __launch_bounds__(256)
void wprep_kernel(const float* __restrict__ W0,
                  const float* __restrict__ W1,
                  const float* __restrict__ W2,
                  _Float16* __restrict__ Wf)
{
    int idx  = blockIdx.x * 256 + threadIdx.x;   // 0..12287
    int lane = idx & 63;
    int frag = idx >> 6;
    int w    = frag >> 6;
    int f    = frag & 63;
    int nt   = f >> 3, kc = f & 7;
    int quad = lane >> 4, lo16 = lane & 15;
    const float* Wp = w == 0 ? W0 : (w == 1 ? W1 : W2);
    half8 v;
#pragma unroll
    for (int jj = 0; jj < 8; jj++)
        v[jj] = (_Float16)Wp[(size_t)(kc * 32 + quad * 8 + jj) * FOUT + nt * 16 + lo16];
    *(half8*)&Wf[(size_t)idx * 8] = v;
}

// ---------------------------------------------------------------------------
// H = fp16(inp@W), H2 = fp16(inp@W2), H3T = fp16((inp@W3)^T). Barrier-free.
// ---------------------------------------------------------------------------
__global__ __launch_bounds__(256, 2)
void gemm3_kernel(const float* __restrict__ inp,
                  const _Float16* __restrict__ Wf,
                  _Float16* __restrict__ H,
                  _Float16* __restrict__ H2,
                  _Float16* __restrict__ H3T)
{
    const int which = blockIdx.z;
    const int c0    = blockIdx.y * 64;
    const _Float16* Wfw = Wf + (size_t)which * 64 * 64 * 8;
    const int r0 = blockIdx.x * 64;
    const int tid  = threadIdx.x;
    const int wave = tid >> 6;
    const int lane = tid & 63;
    const int lo16 = lane & 15;
    const int quad = lane >> 4;
    const int r = r0 + wave * 16 + lo16;

    half8 a[8];
#pragma unroll
    for (int kc = 0; kc < 8; kc++) {
        const float* p = &inp[(size_t)r * FIN + kc * 32 + quad * 8];
        float4 v0 = *(const float4*)p;
        float4 v1 = *(const float4*)(p + 4);
        a[kc][0] = (_Float16)v0.x; a[kc][1] = (_Float16)v0.y;
        a[kc][2] = (_Float16)v0.z; a[kc][3] = (_Float16)v0.w;
        a[kc][4] = (_Float16)v1.x; a[kc][5] = (_Float16)v1.y;
        a[kc][6] = (_Float16)v1.z; a[kc][7] = (_Float16)v1.w;
    }

    floatx4 acc[4];
#pragma unroll
    for (int i = 0; i < 4; i++) acc[i] = (floatx4){0.f, 0.f, 0.f, 0.f};

#pragma unroll
    for (int kc = 0; kc < 8; kc++)
#pragma unroll
        for (int nt = 0; nt < 4; nt++) {
            int ntg = (c0 >> 4) + nt;
            half8 b = *(const half8*)&Wfw[(((size_t)ntg * 8 + kc) * 64 + lane) * 8];
            acc[nt] = __builtin_amdgcn_mfma_f32_16x16x32_f16(a[kc], b, acc[nt], 0, 0, 0);
        }

    const int arow = wave * 16 + quad * 4;
    if (which < 2) {
        _Float16* outp = which == 0 ? H : H2;
#pragma unroll
        for (int nt = 0; nt < 4; nt++)
#pragma unroll
            for (int rr = 0; rr < 4; rr++)
                outp[(size_t)(r0 + arow + rr) * FOUT + c0 + nt * 16 + lo16] = (_Float16)acc[nt][rr];
    } else {
#pragma unroll
        for (int nt = 0; nt < 4; nt++) {
            half4v v;
#pragma unroll
            for (int rr = 0; rr < 4; rr++) v[rr] = (_Float16)acc[nt][rr];
            *(half4v*)&H3T[(size_t)(c0 + nt * 16 + lo16) * N + r0 + arow] = v;
        }
    }
}

// ---------------------------------------------------------------------------
// Repack K/V into frag-major (one-shot, 2 MB each).
// ---------------------------------------------------------------------------
__global__ __launch_bounds__(256)
void repackK_kernel(const _Float16* __restrict__ H2, _Float16* __restrict__ Kf)
{
    int idx  = blockIdx.x * 256 + threadIdx.x;
    int lane = idx & 63;
    int frag = idx >> 6;
    int jb = frag >> 4, f = frag & 15, nt = f >> 2, kc = f & 3;
    int quad = lane >> 4, lo16 = lane & 15;
    half8 v = *(const half8*)&H2[(size_t)(jb * 64 + nt * 16 + lo16) * FOUT + kc * 32 + quad * 8];
    *(half8*)&Kf[(size_t)idx * 8] = v;
}

__global__ __launch_bounds__(256)
void repackV_kernel(const _Float16* __restrict__ H3T, _Float16* __restrict__ Vf)
{
    int idx  = blockIdx.x * 256 + threadIdx.x;
    int lane = idx & 63;
    int frag = idx >> 6;
    int jb = frag >> 4, f = frag & 15, nt = f >> 1, kc = f & 1;
    int quad = lane >> 4, lo16 = lane & 15;
    half8 v = *(const half8*)&H3T[(size_t)(nt * 16 + lo16) * N + jb * 64 + kc * 32 + quad * 8];
    *(half8*)&Vf[(size_t)idx * 8] = v;
}

// ---------------------------------------------------------------------------
// Flash-style masked attention. K/V shared across the block's 4 waves via
// double-buffered LDS (coalesced global->reg->ds_write staging, 1 barrier
// per j-tile). Cuts duplicated VMEM traffic 4x vs per-wave loads.
// ---------------------------------------------------------------------------
template<int JS>
__global__ __launch_bounds__(256, 2)
void attn_kernel(const _Float16* __restrict__ Hq,   // [N][128]
                 const _Float16* __restrict__ Kf,   // frag-major [N/64][16][64][8]
                 const _Float16* __restrict__ Vf,   // frag-major [N/64][16][64][8]
                 const unsigned long long* __restrict__ Msk, // [N][32][4]
                 float* __restrict__ Opart,         // [JS][N][128]
                 float* __restrict__ mpart,         // [JS][N]
                 float* __restrict__ lpart)         // [JS][N]
{
    __shared__ _Float16 KV[2][16384];       // [buf][16 K frags | 16 V frags]
    __shared__ _Float16 Ps[4][16][BN + 8];  // per-wave P transpose

    const int tid  = threadIdx.x;
    const int wave = tid >> 6;
    const int lane = tid & 63;
    const int lo16 = lane & 15;
    const int quad = lane >> 4;
    const int bid  = blockIdx.x;
    const int js   = bid & (JS - 1);      // XCD affinity: same js -> same XCD
    const int ib   = bid / JS;
    const int i0   = ib * BM;
    const int jbeg = js * (N / JS);
    const int e    = lo16 & 3;
    const int lsh  = lo16 >> 2;
    const int NIT  = (N / JS) / BN;

    half8 q[4];
#pragma unroll
    for (int kc = 0; kc < 4; kc++)
        q[kc] = *(const half8*)&Hq[(size_t)(i0 + wave * 16 + lo16) * FOUT + kc * 32 + quad * 8];

    floatx4 O[8];
#pragma unroll
    for (int i = 0; i < 8; i++) O[i] = (floatx4){0.f, 0.f, 0.f, 0.f};
    float m_r[4], l_r[4];
#pragma unroll
    for (int r = 0; r < 4; r++) { m_r[r] = -1e12f; l_r[r] = 0.f; }

    const int arow = i0 + wave * 16 + quad * 4;   // C-layout row base
    const int soff = ((size_t)0, (tid * 8));      // staging offset base (halves)

    // prologue: stage tile 0 into buf 0
    {
        const int jb0 = jbeg >> 6;
        const _Float16* gk = Kf + (size_t)jb0 * 8192;
        const _Float16* gv = Vf + (size_t)jb0 * 8192;
#pragma unroll
        for (int r = 0; r < 4; r++) {
            int off = (r * 256 + tid) * 8;
            *(half8*)&KV[0][off]        = *(const half8*)&gk[off];
            *(half8*)&KV[0][8192 + off] = *(const half8*)&gv[off];
        }
        __syncthreads();
    }

    int cur = 0;
    for (int it = 0; it < NIT; it++) {
        const int j0 = jbeg + it * BN;
        const int grp = (j0 >> 8) * 4;
        const int bofs = ((j0 & 255) >> 2) + lsh;

        // 1. prefetch next tile into registers (coalesced 1KB loads, in
        //    flight while we process the current tile)
        half8 st[8];
        if (it + 1 < NIT) {
            const int jbn = (j0 + BN) >> 6;
            const _Float16* gk = Kf + (size_t)jbn * 8192;
            const _Float16* gv = Vf + (size_t)jbn * 8192;
#pragma unroll
            for (int r = 0; r < 4; r++) {
                int off = (r * 256 + tid) * 8;
                st[r]     = *(const half8*)&gk[off];
                st[r + 4] = *(const half8*)&gv[off];
            }
        }
        unsigned long long mw[4];
#pragma unroll
        for (int r = 0; r < 4; r++)
            mw[r] = Msk[(size_t)(arow + r) * 128 + e + grp];

        // 2. S = Q K^T from LDS frags
        const _Float16* kb = &KV[cur][0];
        const _Float16* vb = &KV[cur][8192];
        floatx4 S[4];
#pragma unroll
        for (int nt = 0; nt < 4; nt++) {
            S[nt] = (floatx4){0.f, 0.f, 0.f, 0.f};
#pragma unroll
            for (int kc = 0; kc < 4; kc++) {
                half8 b = *(const half8*)&kb[((nt * 4 + kc) * 64 + lane) * 8];
                S[nt] = __builtin_amdgcn_mfma_f32_16x16x32_f16(q[kc], b, S[nt], 0, 0, 0);
            }
        }

        // LeakyReLU then bitmask (ref order)
        float sv[4][4];
#pragma unroll
        for (int nt = 0; nt < 4; nt++)
#pragma unroll
            for (int r = 0; r < 4; r++) {
                float ev = S[nt][r];
                ev = ev > 0.f ? ev : 0.2f * ev;
                sv[nt][r] = ((mw[r] >> (bofs + nt * 4)) & 1ull) ? ev : -1e12f;
            }

        // row max: 16-lane butterfly within quad
        float alpha[4];
#pragma unroll
        for (int r = 0; r < 4; r++) {
            float v = fmaxf(fmaxf(sv[0][r], sv[1][r]), fmaxf(sv[2][r], sv[3][r]));
#pragma unroll
            for (int d = 1; d < 16; d <<= 1)
                v = fmaxf(v, __shfl_xor(v, d));
            float mn = fmaxf(m_r[r], v);
            alpha[r] = __expf(m_r[r] - mn);
            m_r[r] = mn;
        }

        // P = exp(sv - m); stash fp16 P in per-wave LDS (C-layout positions)
        float rs[4] = {0.f, 0.f, 0.f, 0.f};
#pragma unroll
        for (int nt = 0; nt < 4; nt++)
#pragma unroll
            for (int r = 0; r < 4; r++) {
                float p = __expf(sv[nt][r] - m_r[r]);
                rs[r] += p;
                Ps[wave][quad * 4 + r][nt * 16 + lo16] = (_Float16)p;
            }
#pragma unroll
        for (int r = 0; r < 4; r++) {
            float v = rs[r];
#pragma unroll
            for (int d = 1; d < 16; d <<= 1)
                v += __shfl_xor(v, d);
            l_r[r] = l_r[r] * alpha[r] + v;
#pragma unroll
            for (int nt = 0; nt < 8; nt++)
                O[nt][r] *= alpha[r];
        }

        // wave-private Ps write -> read ordering
        asm volatile("s_waitcnt lgkmcnt(0)" ::: "memory");

        // O += P V from LDS frags
#pragma unroll
        for (int kc = 0; kc < BN / 32; kc++) {
            half8 pa = *(const half8*)&Ps[wave][lo16][kc * 32 + quad * 8];
#pragma unroll
            for (int nt = 0; nt < 8; nt++) {
                half8 b = *(const half8*)&vb[((nt * 2 + kc) * 64 + lane) * 8];
                O[nt] = __builtin_amdgcn_mfma_f32_16x16x32_f16(pa, b, O[nt], 0, 0, 0);
            }
        }

        // 4. commit prefetched tile to the other buffer; 5. one barrier/iter
        if (it + 1 < NIT) {
            const int nxt = cur ^ 1;
#pragma unroll
            for (int r = 0; r < 4; r++) {
                int off = (r * 256 + tid) * 8;
                *(half8*)&KV[nxt][off]        = st[r];
                *(half8*)&KV[nxt][8192 + off] = st[r + 4];
            }
        }
        __syncthreads();
        cur ^= 1;
    }

#pragma unroll
    for (int nt = 0; nt < 8; nt++)
#pragma unroll
        for (int r = 0; r < 4; r++)
            Opart[((size_t)js * N + arow + r) * FOUT + nt * 16 + lo16] = O[nt][r];
    if (lo16 == 0) {
#pragma unroll
        for (int r = 0; r < 4; r++) {
            mpart[js * N + arow + r] = m_r[r];
            lpart[js * N + arow + r] = l_r[r];
        }
    }
}

// ---------------------------------------------------------------------------
// Combine j-split partials, normalize, ELU, fp32 out.
// ---------------------------------------------------------------------------
template<int JS>
__global__ __launch_bounds__(256)
void combine_kernel(const float* __restrict__ Opart,
                    const float* __restrict__ mpart,
                    const float* __restrict__ lpart,
                    float* __restrict__ out)
{
    int idx = blockIdx.x * 256 + threadIdx.x;
    int i = idx >> 5;
    int c = (idx & 31) << 2;
    float m[JS];
    float M = -3.0e38f;
#pragma unroll
    for (int s = 0; s < JS; s++) { m[s] = mpart[s * N + i]; M = fmaxf(M, m[s]); }
    float w[JS];
    float L = 0.f;
#pragma unroll
    for (int s = 0; s < JS; s++) { w[s] = __expf(m[s] - M); L += lpart[s * N + i] * w[s]; }
    float4 o = {0.f, 0.f, 0.f, 0.f};
#pragma unroll
    for (int s = 0; s < JS; s++) {
        float4 v = *(const float4*)&Opart[((size_t)s * N + i) * FOUT + c];
        o.x += w[s] * v.x; o.y += w[s] * v.y; o.z += w[s] * v.z; o.w += w[s] * v.w;
    }
    float inv = 1.f / L;
    float r0 = o.x * inv, r1 = o.y * inv, r2 = o.z * inv, r3 = o.w * inv;
    float4 res;
    res.x = r0 > 0.f ? r0 : __expf(r0) - 1.f;
    res.y = r1 > 0.f ? r1 : __expf(r1) - 1.f;
    res.z = r2 > 0.f ? r2 : __expf(r2) - 1.f;
    res.w = r3 > 0.f ? r3 : __expf(r3) - 1.f;
    *(float4*)&out[(size_t)i * FOUT + c] = res;
}

// ---------------------------------------------------------------------------
extern "C" void kernel_launch(void* const* d_in, const int* in_sizes, int n_in,
                              void* d_out, int out_size, void* d_ws, size_t ws_size,
                              hipStream_t stream) {
    const float* inp = (const float*)d_in[0];
    const int*   adj = (const int*)d_in[1];
    const float* W0  = (const float*)d_in[2];
    const float* W1  = (const float*)d_in[3];
    const float* W2  = (const float*)d_in[4];
    float* out = (float*)d_out;

    char* ws = (char*)d_ws;
    _Float16* H   = (_Float16*)(ws);                          // 2 MB
    _Float16* H2  = (_Float16*)(ws + (2u << 20));             // 2 MB
    _Float16* H3T = (_Float16*)(ws + (4u << 20));             // 2 MB
    _Float16* Wf  = (_Float16*)(ws + (6u << 20));             // 192 KB
    unsigned long long* Msk = (unsigned long long*)(ws + (7u << 20)); // 8 MB
    _Float16* Kf  = (_Float16*)(ws + (15u << 20));            // 2 MB
    _Float16* Vf  = (_Float16*)(ws + (17u << 20));            // 2 MB
    float* Opart  = (float*)(ws + (19u << 20));               // JS*4 MB

    const size_t need8 = (19ull << 20) + 8ull * N * FOUT * 4 + 2ull * 8 * N * 4;

    maskprep_kernel<<<16384, 256, 0, stream>>>(adj, Msk);
    wprep_kernel<<<48, 256, 0, stream>>>(W0, W1, W2, Wf);
    gemm3_kernel<<<dim3(N / 64, 2, 3), 256, 0, stream>>>(inp, Wf, H, H2, H3T);
    repackK_kernel<<<512, 256, 0, stream>>>(H2, Kf);
    repackV_kernel<<<512, 256, 0, stream>>>(H3T, Vf);

    if (ws_size >= need8) {
        constexpr int JS = 8;
        float* mpart = (float*)(ws + (19u << 20) + (size_t)JS * N * FOUT * 4);
        float* lpart = mpart + (size_t)JS * N;
        attn_kernel<JS><<<(N / BM) * JS, 256, 0, stream>>>(H, Kf, Vf, Msk, Opart, mpart, lpart);
        combine_kernel<JS><<<(N * FOUT / 4) / 256, 256, 0, stream>>>(Opart, mpart, lpart, out);
    } else {
        constexpr int JS = 4;
        float* mpart = (float*)(ws + (19u << 20) + (size_t)JS * N * FOUT * 4);
        float* lpart = mpart + (size_t)JS * N;
        attn_kernel<JS><<<(N / BM) * JS, 256, 0, stream>>>(H, Kf, Vf, Msk, Opart, mpart, lpart);
        combine_kernel<JS><<<(N * FOUT / 4) / 256, 256, 0, stream>>>(Opart, mpart, lpart, out);
    }
}